// Round 3
// baseline (7416.209 us; speedup 1.0000x reference)
//
#include <hip/hip_runtime.h>
#include <hip/hip_bf16.h>
#include <math.h>

#define EMBED  512
#define HIDDEN 512
#define OUTF   100
#define BATCH  500
#define TSTEPS 256
#define XROW   (TSTEPS * EMBED)
#define WFRAG  1048576          // elems per weight frag matrix: 64nt * 32k16 * 64lane * 8
#define HFRAG  262144           // elems per h frag buffer: 16mt * 32k16 * 64lane * 8

typedef __bf16 v8bf   __attribute__((ext_vector_type(8)));
typedef float  f32x16 __attribute__((ext_vector_type(16)));
typedef unsigned long long u64;

__device__ __forceinline__ float sigm_(float v){ return 1.f/(1.f+__expf(-v)); }
__device__ __forceinline__ float tanh_(float v){ return 1.f - 2.f/(__expf(2.f*v)+1.f); }

// Agent-scope (cross-XCD coherent) 16-byte h-fragment load: two b64 atomics.
__device__ __forceinline__ v8bf h_load(const __bf16* p){
    union { v8bf v; u64 q[2]; } u;
    u.q[0] = __hip_atomic_load((const u64*)p,     __ATOMIC_RELAXED, __HIP_MEMORY_SCOPE_AGENT);
    u.q[1] = __hip_atomic_load((const u64*)p + 1, __ATOMIC_RELAXED, __HIP_MEMORY_SCOPE_AGENT);
    return u.v;
}

// ---------------------------------------------------------------------------
// One-time weight conversion to bf16 MFMA B-fragment order (layout verified R2):
//   frag elem ((nt*32 + k16)*64 + lane)*8 + slot, row = nt*32+(lane&31),
//   k = k16*16 + (lane>>5)*8 + slot
// ---------------------------------------------------------------------------
__global__ __launch_bounds__(256) void convert_w(
    const float* __restrict__ Wih, const float* __restrict__ Whh,
    __bf16* __restrict__ wf_ih, __bf16* __restrict__ wf_hh)
{
    const int idx   = blockIdx.x * 256 + threadIdx.x;   // 0..262143
    const int which = idx >> 17;
    const int s     = idx & 131071;
    const int lane  = s & 63;
    const int k16   = (s >> 6) & 31;
    const int nt    = s >> 11;
    const int row   = nt * 32 + (lane & 31);
    const int k     = k16 * 16 + ((lane >> 5) << 3);
    const float* W  = which ? Whh : Wih;
    __bf16* dst     = which ? wf_hh : wf_ih;
    const float* p  = W + (long)row * 512 + k;
    const float4 f0 = *(const float4*)p;
    const float4 f1 = *(const float4*)(p + 4);
    v8bf v;
    v[0]=(__bf16)f0.x; v[1]=(__bf16)f0.y; v[2]=(__bf16)f0.z; v[3]=(__bf16)f0.w;
    v[4]=(__bf16)f1.x; v[5]=(__bf16)f1.y; v[6]=(__bf16)f1.z; v[7]=(__bf16)f1.w;
    *(v8bf*)&dst[(long)s * 8] = v;
}

__global__ __launch_bounds__(256) void convert_wfc(
    const float* __restrict__ Wfc, __bf16* __restrict__ wf_fc)
{
    const int s    = blockIdx.x * 256 + threadIdx.x;    // 0..8191 (4 nt)
    const int lane = s & 63;
    const int k16  = (s >> 6) & 31;
    const int nt   = s >> 11;
    const int row  = nt * 32 + (lane & 31);
    const int k    = k16 * 16 + ((lane >> 5) << 3);
    v8bf v;
    if (row < OUTF) {
        const float* p  = Wfc + (long)row * 512 + k;
        const float4 f0 = *(const float4*)p;
        const float4 f1 = *(const float4*)(p + 4);
        v[0]=(__bf16)f0.x; v[1]=(__bf16)f0.y; v[2]=(__bf16)f0.z; v[3]=(__bf16)f0.w;
        v[4]=(__bf16)f1.x; v[5]=(__bf16)f1.y; v[6]=(__bf16)f1.z; v[7]=(__bf16)f1.w;
    } else {
        #pragma unroll
        for (int j = 0; j < 8; ++j) v[j] = (__bf16)0.f;
    }
    *(v8bf*)&wf_fc[(long)s * 8] = v;
}

// ---------------------------------------------------------------------------
// Persistent LSTM: 256 blocks (ht = bid&15, mt = bid>>4), 4 waves = 4 gates.
// Entire 256-step scan in one launch; per-step software grid barrier.
// c-state in registers; h exchanged via agent-scope atomics in frag layout.
// Blocks ht<4 additionally compute the FC head for out[t-1].
// ---------------------------------------------------------------------------
__global__ __launch_bounds__(256) void lstm_persist(
    const float* __restrict__ x,
    const __bf16* __restrict__ wf_ih, const __bf16* __restrict__ wf_hh,
    const __bf16* __restrict__ wf_fc,
    const float* __restrict__ bih, const float* __restrict__ bhh,
    const float* __restrict__ bfc,
    __bf16* __restrict__ hbuf0, __bf16* __restrict__ hbuf1,
    unsigned* __restrict__ cnt,
    float* __restrict__ out)
{
    __shared__ float Gs[4][32][36];   // gate/FC exchange; 2-way-max bank aliasing on writes

    const int tid  = threadIdx.x;
    const int lane = tid & 63;
    const int w    = tid >> 6;                 // gate (i,f,g,o) / FC K-split slice
    const int ht   = blockIdx.x & 15;
    const int mt   = blockIdx.x >> 4;
    const int col  = lane & 31;
    const int half = lane >> 5;

    const int  arow   = mt * 32 + col;         // A-frag row staged by this lane
    const bool avalid = arow < BATCH;
    const float* xbase = x + (long)(avalid ? arow : 0) * XROW + (half << 3);

    const __bf16* wih_b = wf_ih + (long)(w * 16 + ht) * 16384 + lane * 8;
    const __bf16* whh_b = wf_hh + (long)(w * 16 + ht) * 16384 + lane * 8;
    const long hfb = (long)(mt * 32) * 512 + lane * 8;

    const int gidx   = w * 512 + ht * 32 + col;
    const float bias = bih[gidx] + bhh[gidx];

    // cell-update mapping: thread -> (row cm, 4 hidden cols at cnb)
    const int cm  = tid >> 3;
    const int cnb = (tid & 7) << 2;
    const int cb  = mt * 32 + cm;
    const int hk  = ht * 2 + (cnb >> 4);                       // frag k16 of hidden col
    const int hl  = ((cnb >> 3) & 1) * 32 + cm;                // frag lane
    const long hoo = ((long)(mt * 32 + hk) * 64 + hl) * 8 + (cnb & 7);
    float cr0 = 0.f, cr1 = 0.f, cr2 = 0.f, cr3 = 0.f;

    v8bf zer;
    #pragma unroll
    for (int j = 0; j < 8; ++j) zer[j] = (__bf16)0.f;

    auto do_fc = [&](const __bf16* hsrc, int tprev){
        f32x16 fa;
        #pragma unroll
        for (int j = 0; j < 16; ++j) fa[j] = 0.f;
        const __bf16* wfc_b = wf_fc + (long)ht * 16384 + lane * 8;
        #pragma unroll
        for (int i = 0; i < 8; ++i) {
            const int k = w * 8 + i;                           // 4-way K split
            const v8bf ah = h_load(hsrc + hfb + (long)k * 512);
            const v8bf bf = *(const v8bf*)(wfc_b + (long)k * 512);
            fa = __builtin_amdgcn_mfma_f32_32x32x16_bf16(ah, bf, fa, 0, 0, 0);
        }
        #pragma unroll
        for (int r = 0; r < 16; ++r) {
            const int m = (r & 3) + 8 * (r >> 2) + 4 * half;
            Gs[w][m][col] = fa[r];
        }
        __syncthreads();
        const int o0 = ht * 32 + cnb;
        if (cb < BATCH && o0 < OUTF) {
            const float4 s0 = *(const float4*)&Gs[0][cm][cnb];
            const float4 s1 = *(const float4*)&Gs[1][cm][cnb];
            const float4 s2 = *(const float4*)&Gs[2][cm][cnb];
            const float4 s3 = *(const float4*)&Gs[3][cm][cnb];
            const float4 bb = *(const float4*)(bfc + o0);
            float4 ov;
            ov.x = sigm_(s0.x + s1.x + s2.x + s3.x + bb.x);
            ov.y = sigm_(s0.y + s1.y + s2.y + s3.y + bb.y);
            ov.z = sigm_(s0.z + s1.z + s2.z + s3.z + bb.z);
            ov.w = sigm_(s0.w + s1.w + s2.w + s3.w + bb.w);
            *(float4*)(out + (long)cb * (TSTEPS * OUTF) + (long)tprev * OUTF + o0) = ov;
        }
    };

    for (int t = 0; t < TSTEPS; ++t) {
        const __bf16* hin  = (t & 1) ? hbuf1 : hbuf0;
        __bf16*       hout = (t & 1) ? hbuf0 : hbuf1;

        f32x16 a0, a1;
        #pragma unroll
        for (int j = 0; j < 16; ++j) { a0[j] = 0.f; a1[j] = 0.f; }

        const float* xp = xbase + (long)t * EMBED;
        #pragma unroll 4
        for (int k = 0; k < 32; ++k) {
            const v8bf bi = *(const v8bf*)(wih_b + (long)k * 512);
            const v8bf bh = *(const v8bf*)(whh_b + (long)k * 512);
            const v8bf ah = h_load(hin + hfb + (long)k * 512);
            v8bf ax = zer;
            if (avalid) {
                const float4 x0 = *(const float4*)(xp + k * 16);
                const float4 x1 = *(const float4*)(xp + k * 16 + 4);
                ax[0]=(__bf16)x0.x; ax[1]=(__bf16)x0.y; ax[2]=(__bf16)x0.z; ax[3]=(__bf16)x0.w;
                ax[4]=(__bf16)x1.x; ax[5]=(__bf16)x1.y; ax[6]=(__bf16)x1.z; ax[7]=(__bf16)x1.w;
            }
            a0 = __builtin_amdgcn_mfma_f32_32x32x16_bf16(ax, bi, a0, 0, 0, 0);
            a1 = __builtin_amdgcn_mfma_f32_32x32x16_bf16(ah, bh, a1, 0, 0, 0);
        }

        // gates -> LDS exchange (verified C/D mapping)
        #pragma unroll
        for (int r = 0; r < 16; ++r) {
            const int m = (r & 3) + 8 * (r >> 2) + 4 * half;
            Gs[w][m][col] = a0[r] + a1[r] + bias;
        }
        __syncthreads();

        // cell update; h out as bf16 frag via agent-scope atomic (MALL-coherent)
        {
            const float4 gi = *(const float4*)&Gs[0][cm][cnb];
            const float4 gf = *(const float4*)&Gs[1][cm][cnb];
            const float4 gg = *(const float4*)&Gs[2][cm][cnb];
            const float4 go = *(const float4*)&Gs[3][cm][cnb];
            float4 hv;
            cr0 = sigm_(gf.x)*cr0 + sigm_(gi.x)*tanh_(gg.x); hv.x = sigm_(go.x)*tanh_(cr0);
            cr1 = sigm_(gf.y)*cr1 + sigm_(gi.y)*tanh_(gg.y); hv.y = sigm_(go.y)*tanh_(cr1);
            cr2 = sigm_(gf.z)*cr2 + sigm_(gi.z)*tanh_(gg.z); hv.z = sigm_(go.z)*tanh_(cr2);
            cr3 = sigm_(gf.w)*cr3 + sigm_(gi.w)*tanh_(gg.w); hv.w = sigm_(go.w)*tanh_(cr3);
            union { u64 q; __bf16 b4[4]; } z;
            z.b4[0]=(__bf16)hv.x; z.b4[1]=(__bf16)hv.y; z.b4[2]=(__bf16)hv.z; z.b4[3]=(__bf16)hv.w;
            __hip_atomic_store((u64*)(hout + hoo), z.q, __ATOMIC_RELAXED, __HIP_MEMORY_SCOPE_AGENT);
        }

        // FC head for step t-1 (overlaps other blocks' gates work)
        if (ht < 4 && t > 0) {
            __syncthreads();          // cell's Gs reads done before FC reuses Gs
            do_fc(hin, t - 1);
        }

        // ---- grid barrier. __syncthreads drains vmcnt(0) => h stores visible
        // at MALL before the counter increment; readers use MALL atomics, so
        // no cache-wide fence needed (weights stay L2-resident).
        __syncthreads();
        if (tid == 0) {
            __hip_atomic_fetch_add(cnt, 1u, __ATOMIC_RELAXED, __HIP_MEMORY_SCOPE_AGENT);
            const unsigned tgt = (unsigned)(t + 1) * 256u;
            unsigned sp = 0;
            while (__hip_atomic_load(cnt, __ATOMIC_RELAXED, __HIP_MEMORY_SCOPE_AGENT) < tgt) {
                __builtin_amdgcn_s_sleep(2);
                if (++sp > 400000u) break;   // wrong-answer escape hatch, not a hang
            }
        }
        __syncthreads();
    }

    // tail: out[255] from h_255 (sits in hbuf0 after step 255)
    if (ht < 4) do_fc(hbuf0, TSTEPS - 1);
}

extern "C" void kernel_launch(void* const* d_in, const int* in_sizes, int n_in,
                              void* d_out, int out_size, void* d_ws, size_t ws_size,
                              hipStream_t stream) {
    const float* x   = (const float*)d_in[0];
    const float* Wih = (const float*)d_in[1];
    const float* Whh = (const float*)d_in[2];
    const float* bih = (const float*)d_in[3];
    const float* bhh = (const float*)d_in[4];
    const float* Wfc = (const float*)d_in[5];
    const float* bfc = (const float*)d_in[6];
    float* out = (float*)d_out;

    // ws: [wf_ih 2MB][wf_hh 2MB][wf_fc 128KB][hbuf0 512KB][hbuf1 512KB][cnt]
    __bf16* wf_ih = (__bf16*)d_ws;
    __bf16* wf_hh = wf_ih + WFRAG;
    __bf16* wf_fc = wf_hh + WFRAG;
    __bf16* hbuf0 = wf_fc + 65536;
    __bf16* hbuf1 = hbuf0 + HFRAG;
    unsigned* cnt = (unsigned*)(hbuf1 + HFRAG);

    hipMemsetAsync(hbuf0, 0, (size_t)HFRAG * sizeof(__bf16), stream);  // h_{-1} = 0
    hipMemsetAsync(cnt, 0, 64, stream);                                // barrier counter

    convert_w<<<1024, 256, 0, stream>>>(Wih, Whh, wf_ih, wf_hh);
    convert_wfc<<<32, 256, 0, stream>>>(Wfc, wf_fc);
    lstm_persist<<<256, 256, 0, stream>>>(x, wf_ih, wf_hh, wf_fc,
                                          bih, bhh, bfc, hbuf0, hbuf1, cnt, out);
}